// Round 10
// baseline (108.905 us; speedup 1.0000x reference)
//
#include <hip/hip_runtime.h>
#include <math.h>

#define S_ 4
#define C_ 384
#define H_ 96
#define W_ 96
#define B_ 8
#define M_ 64
#define HW_ (H_ * W_)
#define EPSV 1e-6f
#define BETA_V 0.3f
#define TEMP_V 0.07f

#define NB_Q (B_ * HW_ / 64)      // 1152 q-sqnorm blocks (64 px each)
#define NB_A (S_ * C_)            // 1536 feats plane-sum blocks
#define NB_B (M_ * (C_ / 4))      // 6144 window blocks (round-3 form)
#define NB_K1 (NB_Q + NB_A + NB_B + 1)
#define NB_K3 (B_ * HW_ / 64)     // 1152 dot blocks

__device__ __forceinline__ float wave_sum(float v) {
#pragma unroll
    for (int o = 32; o; o >>= 1) v += __shfl_down(v, o, 64);
    return v;
}

__device__ __forceinline__ float block_sum(float v) {
    __shared__ float sm[4];
    int lane = threadIdx.x & 63;
    int wid = threadIdx.x >> 6;
    v = wave_sum(v);
    if (lane == 0) sm[wid] = v;
    __syncthreads();
    float r = sm[0] + sm[1] + sm[2] + sm[3];
    __syncthreads();
    return r;
}

// K1: ONE dispatch streams BOTH cold inputs concurrently.
//  role Q  [0, 1152):        per-pixel ||q||^2 (reads query, no v needed)
//  role A  [1152, 2688):     per-(s,c) masked plane sums (reads feats cold)
//  role B  [2688, 8832):     per-(anchor, 4ch) window sums (feats via L2/L3)
//  role FG [8832]:           mask total
// Role order: Q and A first so both HBM streams run concurrently; B's
// L3-tier re-reads hide under the cold streams.
__global__ __launch_bounds__(256) void k_stream(const float* __restrict__ q,
                                                const float* __restrict__ feats,
                                                const int* __restrict__ mask,
                                                const int* __restrict__ pos,
                                                const int* __restrict__ samp,
                                                const int* __restrict__ rad,
                                                float* __restrict__ qsq,
                                                float* __restrict__ partial,
                                                float* __restrict__ proto,
                                                float* __restrict__ msum_out,
                                                float* __restrict__ fg_out) {
    int bid = blockIdx.x;
    int t = threadIdx.x;
    int wid = t >> 6;
    int lane = t & 63;

    if (bid < NB_Q) {
        // ---- role Q: ||q||^2 for 64 pixels; 4 waves split channels
        __shared__ float ssq[4][64];
        int b = bid / (HW_ / 64);
        int p0 = (bid - b * (HW_ / 64)) * 64;
        const float* qp = q + ((size_t)b * C_ + wid * 96) * HW_ + p0 + lane;
        float sq = 0.0f;
#pragma unroll 8
        for (int c = 0; c < 96; ++c) {
            float val = qp[(size_t)c * HW_];
            sq += val * val;
        }
        ssq[wid][lane] = sq;
        __syncthreads();
        if (wid == 0)
            qsq[(size_t)b * HW_ + p0 + lane] =
                ssq[0][lane] + ssq[1][lane] + ssq[2][lane] + ssq[3][lane];
        return;
    }
    bid -= NB_Q;
    if (bid < NB_A) {
        // ---- role A: partial[sc] = sum_p feats[s,c,p] * mask[s,p]
        int s = bid / C_;
        const float4* fp = (const float4*)(feats + (size_t)bid * HW_);
        const int4* mp = (const int4*)(mask + (size_t)s * HW_);
        float acc = 0.0f;
#pragma unroll
        for (int k = 0; k < HW_ / 4 / 256; ++k) {  // 9 iterations
            int i = t + k * 256;
            float4 f = fp[i];
            int4 m = mp[i];
            acc += f.x * (float)m.x + f.y * (float)m.y + f.z * (float)m.z + f.w * (float)m.w;
        }
        float tot = block_sum(acc);
        if (t == 0) partial[bid] = tot;
        return;
    }
    bid -= NB_A;
    if (bid < NB_B) {
        // ---- role B: one block per (anchor m, channel-group of 4)
        const int CG = C_ / 4;  // 96
        int m = bid / CG;
        int cg = bid % CG;
        int y = pos[2 * m + 0];
        int x = pos[2 * m + 1];
        int s = samp[m];
        int ri = rad[m];
        int r = (ri == 0) ? 4 : (ri == 1) ? 8 : 16;
        int y0 = max(y - r, 0), y1 = min(y + r + 1, H_);
        int x0 = max(x - r, 0), x1 = min(x + r + 1, W_);
        int ww = x1 - x0;
        int n = (y1 - y0) * ww;

        __shared__ float mwin[33 * 33];
        const int* mp = mask + (size_t)s * HW_;
        float macc = 0.0f;
        {
            int yy = t / ww;
            int xx = t - yy * ww;
            int dy = 256 / ww, dx = 256 - dy * ww;  // dx < ww
            for (int i = t; i < n; i += 256) {
                float mv = (float)mp[(y0 + yy) * W_ + x0 + xx];
                mwin[i] = mv;
                macc += mv;
                xx += dx; yy += dy;
                if (xx >= ww) { xx -= ww; ++yy; }
            }
        }
        float msumv = block_sum(macc);  // internal barrier publishes mwin
        if (cg == 0 && t == 0) msum_out[m] = msumv;
        float inv = 1.0f / (msumv + EPSV);

        int c = cg * 4 + wid;
        const float* fp = feats + ((size_t)s * C_ + c) * HW_;
        float acc = 0.0f;
        {
            int yy = lane / ww;
            int xx = lane - yy * ww;
            int dy = 64 / ww, dx = 64 - dy * ww;
            for (int i = lane; i < n; i += 64) {
                acc += fp[(y0 + yy) * W_ + x0 + xx] * mwin[i];
                xx += dx; yy += dy;
                if (xx >= ww) { xx -= ww; ++yy; }
            }
        }
        acc = wave_sum(acc);
        if (lane == 0) proto[m * C_ + c] = acc * inv;
        return;
    }
    // ---- role FG: total mask sum
    const int4* mp4 = (const int4*)mask;
    float acc = 0.0f;
    for (int i = t; i < S_ * HW_ / 4; i += 256) {
        int4 m = mp4[i];
        acc += (float)(m.x + m.y + m.z + m.w);
    }
    float fg = block_sum(acc);
    if (t == 0) fg_out[0] = fg;
}

// K2: single block builds combined vector v (proven round-3 form).
__global__ __launch_bounds__(256) void k_finalize(const float* __restrict__ partial,
                                                  const float* __restrict__ msum,
                                                  const float* __restrict__ proto,
                                                  const float* __restrict__ fg_in,
                                                  float* __restrict__ v) {
    int tid = threadIdx.x;
    int wid = tid >> 6;
    int lane = tid & 63;

    float invfg = 1.0f / (fg_in[0] + EPSV);

    __shared__ float gv[C_];
    for (int c = tid; c < C_; c += 256) {
        float tv = 0.0f;
        for (int s = 0; s < S_; ++s) tv += partial[s * C_ + c];
        gv[c] = tv * invfg;
    }
    __syncthreads();

    float sq = 0.0f;
    for (int c = tid; c < C_; c += 256) sq += gv[c] * gv[c];
    float gn = block_sum(sq);
    gn = fmaxf(sqrtf(gn), 1e-12f);

    float wa = (tid < M_) ? msum[tid] : 0.0f;
    float T = block_sum(wa);
    float wb = (tid < M_) ? msum[tid] / (T + EPSV) : 0.0f;
    float wsum = block_sum(wb);

    __shared__ float pn[M_];
    for (int m = wid; m < M_; m += 4) {
        float a = 0.0f;
        for (int c = lane; c < C_; c += 64) {
            float p = proto[m * C_ + c];
            a += p * p;
        }
        a = wave_sum(a);
        if (lane == 0) pn[m] = fmaxf(sqrtf(a), 1e-12f);
    }
    __syncthreads();

    __shared__ float wq[M_];
    if (tid < M_) {
        float w = (msum[tid] / (T + EPSV)) / (wsum + EPSV);
        wq[tid] = w / pn[tid];
    }
    __syncthreads();

    for (int c = tid; c < C_; c += 256) {
        float vl = 0.0f;
        for (int m = 0; m < M_; ++m) vl += wq[m] * proto[m * C_ + c];
        v[c] = BETA_V * (gv[c] / gn) + (1.0f - BETA_V) * vl;
    }
}

// K3: dot-only score; q is L3-resident from K1. 64 px/block, 4-wave split.
__global__ __launch_bounds__(256) void k_dot(const float* __restrict__ q,
                                             const float* __restrict__ v,
                                             const float* __restrict__ qsq,
                                             float* __restrict__ out) {
    __shared__ float vs[C_];
    __shared__ float sd[4][64];
    for (int c = threadIdx.x; c < C_; c += 256) vs[c] = v[c];
    __syncthreads();

    int t = threadIdx.x;
    int wid = t >> 6;
    int lane = t & 63;
    int b = blockIdx.x / (HW_ / 64);
    int p0 = (blockIdx.x - b * (HW_ / 64)) * 64;
    const float* qp = q + ((size_t)b * C_ + wid * 96) * HW_ + p0 + lane;

    float dot = 0.0f;
#pragma unroll 8
    for (int c = 0; c < 96; ++c) {
        float val = qp[(size_t)c * HW_];
        dot += val * vs[wid * 96 + c];
    }
    sd[wid][lane] = dot;
    __syncthreads();
    if (wid == 0) {
        float d = sd[0][lane] + sd[1][lane] + sd[2][lane] + sd[3][lane];
        float s2 = qsq[(size_t)b * HW_ + p0 + lane];
        float sv = d / fmaxf(sqrtf(s2), 1e-12f);
        float o = sv / TEMP_V;
        float* ob = out + (size_t)b * 2 * HW_;
        ob[p0 + lane] = -o;
        ob[HW_ + p0 + lane] = o;
    }
}

extern "C" void kernel_launch(void* const* d_in, const int* in_sizes, int n_in,
                              void* d_out, int out_size, void* d_ws, size_t ws_size,
                              hipStream_t stream) {
    const float* support_feats = (const float*)d_in[0];
    const int* support_masks = (const int*)d_in[1];
    const float* query_feats = (const float*)d_in[2];
    const int* anchor_pos = (const int*)d_in[3];
    const int* anchor_sample = (const int*)d_in[4];
    const int* anchor_radius = (const int*)d_in[5];
    float* out = (float*)d_out;

    float* ws = (float*)d_ws;
    float* ws_partial = ws;                 // S*C = 1536
    float* ws_msum = ws_partial + S_ * C_;  // 64
    float* ws_proto = ws_msum + M_;         // M*C = 24576
    float* ws_v = ws_proto + M_ * C_;       // 384
    float* ws_fg = ws_v + C_;               // 1
    float* ws_qsq = ws_fg + 1;              // B*HW = 73728

    k_stream<<<NB_K1, 256, 0, stream>>>(query_feats, support_feats, support_masks,
                                        anchor_pos, anchor_sample, anchor_radius,
                                        ws_qsq, ws_partial, ws_proto, ws_msum, ws_fg);
    k_finalize<<<1, 256, 0, stream>>>(ws_partial, ws_msum, ws_proto, ws_fg, ws_v);
    k_dot<<<NB_K3, 256, 0, stream>>>(query_feats, ws_v, ws_qsq, out);
}

// Round 11
// 101.468 us; speedup vs baseline: 1.0733x; 1.0733x over previous
//
#include <hip/hip_runtime.h>
#include <math.h>

#define S_ 4
#define C_ 384
#define H_ 96
#define W_ 96
#define B_ 8
#define M_ 64
#define HW_ (H_ * W_)
#define EPSV 1e-6f
#define BETA_V 0.3f
#define TEMP_V 0.07f

#define NB_A (S_ * C_)            // 1536 plane-sum blocks
#define NB_B (M_ * (C_ / 4))      // 6144 window blocks
#define NB_PREP (NB_A + NB_B + 1)

#define NCH 32                    // channel chunks for score pass 1
#define CCH (C_ / NCH)            // 12 channels per chunk
#define NPART 3                   // pixel thirds
#define PT (HW_ / NPART)          // 3072 px per part
#define NB_S1 (B_ * NCH * NPART)  // 768
#define NB_S2 (B_ * HW_ / 256)    // 288

__device__ __forceinline__ float wave_sum(float v) {
#pragma unroll
    for (int o = 32; o; o >>= 1) v += __shfl_down(v, o, 64);
    return v;
}

__device__ __forceinline__ float block_sum(float v) {
    __shared__ float sm[4];
    int lane = threadIdx.x & 63;
    int wid = threadIdx.x >> 6;
    v = wave_sum(v);
    if (lane == 0) sm[wid] = v;
    __syncthreads();
    float r = sm[0] + sm[1] + sm[2] + sm[3];
    __syncthreads();
    return r;
}

// k_prep: round-3 proven form (~26 us measured via round-8 x2 replication).
__global__ __launch_bounds__(256) void k_prep(const float* __restrict__ feats,
                                              const int* __restrict__ mask,
                                              const int* __restrict__ pos,
                                              const int* __restrict__ samp,
                                              const int* __restrict__ rad,
                                              float* __restrict__ partial,
                                              float* __restrict__ proto,
                                              float* __restrict__ msum_out,
                                              float* __restrict__ fg_out) {
    int bid = blockIdx.x;
    int t = threadIdx.x;

    if (bid < NB_A) {
        // ---- role A: partial[sc] = sum_p feats[s,c,p] * mask[s,p]
        int s = bid / C_;
        const float4* fp = (const float4*)(feats + (size_t)bid * HW_);
        const int4* mp = (const int4*)(mask + (size_t)s * HW_);
        float acc = 0.0f;
#pragma unroll
        for (int k = 0; k < HW_ / 4 / 256; ++k) {  // 9 iterations
            int i = t + k * 256;
            float4 f = fp[i];
            int4 m = mp[i];
            acc += f.x * (float)m.x + f.y * (float)m.y + f.z * (float)m.z + f.w * (float)m.w;
        }
        float tot = block_sum(acc);
        if (t == 0) partial[bid] = tot;
        return;
    }
    bid -= NB_A;
    if (bid < NB_B) {
        // ---- role B: one block per (anchor m, channel-group of 4)
        const int CG = C_ / 4;  // 96
        int m = bid / CG;
        int cg = bid % CG;
        int y = pos[2 * m + 0];
        int x = pos[2 * m + 1];
        int s = samp[m];
        int ri = rad[m];
        int r = (ri == 0) ? 4 : (ri == 1) ? 8 : 16;
        int y0 = max(y - r, 0), y1 = min(y + r + 1, H_);
        int x0 = max(x - r, 0), x1 = min(x + r + 1, W_);
        int ww = x1 - x0;
        int n = (y1 - y0) * ww;

        __shared__ float mwin[33 * 33];
        const int* mp = mask + (size_t)s * HW_;
        float macc = 0.0f;
        {
            int yy = t / ww;
            int xx = t - yy * ww;
            int dy = 256 / ww, dx = 256 - dy * ww;  // dx < ww
            for (int i = t; i < n; i += 256) {
                float mv = (float)mp[(y0 + yy) * W_ + x0 + xx];
                mwin[i] = mv;
                macc += mv;
                xx += dx; yy += dy;
                if (xx >= ww) { xx -= ww; ++yy; }
            }
        }
        float msumv = block_sum(macc);  // internal barrier publishes mwin
        if (cg == 0 && t == 0) msum_out[m] = msumv;
        float inv = 1.0f / (msumv + EPSV);

        int wid = t >> 6;
        int lane = t & 63;
        int c = cg * 4 + wid;
        const float* fp = feats + ((size_t)s * C_ + c) * HW_;
        float acc = 0.0f;
        {
            int yy = lane / ww;
            int xx = lane - yy * ww;
            int dy = 64 / ww, dx = 64 - dy * ww;
            for (int i = lane; i < n; i += 64) {
                acc += fp[(y0 + yy) * W_ + x0 + xx] * mwin[i];
                xx += dx; yy += dy;
                if (xx >= ww) { xx -= ww; ++yy; }
            }
        }
        acc = wave_sum(acc);
        if (lane == 0) proto[m * C_ + c] = acc * inv;
        return;
    }
    // ---- role C: fg = total mask sum
    const int4* mp4 = (const int4*)mask;
    float acc = 0.0f;
    for (int i = t; i < S_ * HW_ / 4; i += 256) {
        int4 m = mp4[i];
        acc += (float)(m.x + m.y + m.z + m.w);
    }
    float fg = block_sum(acc);
    if (t == 0) fg_out[0] = fg;
}

// Single block: combine into the final C-vector v.
__global__ __launch_bounds__(256) void k_finalize(const float* __restrict__ partial,
                                                  const float* __restrict__ msum,
                                                  const float* __restrict__ proto,
                                                  const float* __restrict__ fg_in,
                                                  float* __restrict__ v) {
    int tid = threadIdx.x;
    int wid = tid >> 6;
    int lane = tid & 63;

    float invfg = 1.0f / (fg_in[0] + EPSV);

    __shared__ float gv[C_];
    for (int c = tid; c < C_; c += 256) {
        float tv = 0.0f;
        for (int s = 0; s < S_; ++s) tv += partial[s * C_ + c];
        gv[c] = tv * invfg;
    }
    __syncthreads();

    float sq = 0.0f;
    for (int c = tid; c < C_; c += 256) sq += gv[c] * gv[c];
    float gn = block_sum(sq);
    gn = fmaxf(sqrtf(gn), 1e-12f);

    float wa = (tid < M_) ? msum[tid] : 0.0f;
    float T = block_sum(wa);
    float wb = (tid < M_) ? msum[tid] / (T + EPSV) : 0.0f;
    float wsum = block_sum(wb);

    __shared__ float pn[M_];
    for (int m = wid; m < M_; m += 4) {
        float a = 0.0f;
        for (int c = lane; c < C_; c += 64) {
            float p = proto[m * C_ + c];
            a += p * p;
        }
        a = wave_sum(a);
        if (lane == 0) pn[m] = fmaxf(sqrtf(a), 1e-12f);
    }
    __syncthreads();

    __shared__ float wq[M_];
    if (tid < M_) {
        float w = (msum[tid] / (T + EPSV)) / (wsum + EPSV);
        wq[tid] = w / pn[tid];
    }
    __syncthreads();

    for (int c = tid; c < C_; c += 256) {
        float vl = 0.0f;
        for (int m = 0; m < M_; ++m) vl += wq[m] * proto[m * C_ + c];
        v[c] = BETA_V * (gv[c] / gn) + (1.0f - BETA_V) * vl;
    }
}

// Score pass 1 (round-8 proven form, ~28 us cold): block = (b, 12-channel
// chunk, pixel third); streams contiguous 12 KB rows, float4, partials to ws.
__global__ __launch_bounds__(256) void k_score1(const float* __restrict__ q,
                                                const float* __restrict__ v,
                                                float* __restrict__ wsd,
                                                float* __restrict__ wss) {
    int bid = blockIdx.x;
    int part = bid % NPART;
    int bc = bid / NPART;
    int ch = bc % NCH;
    int b = bc / NCH;
    int t = threadIdx.x;
    int pxb = part * PT;

    float vcs[CCH];
#pragma unroll
    for (int j = 0; j < CCH; ++j) vcs[j] = v[ch * CCH + j];

    float4 d0 = {0.f, 0.f, 0.f, 0.f}, d1 = d0, d2 = d0;
    float4 s0 = d0, s1 = d0, s2 = d0;
#pragma unroll 2
    for (int j = 0; j < CCH; ++j) {
        int c = ch * CCH + j;
        float vc = vcs[j];
        const float4* qc = (const float4*)(q + ((size_t)b * C_ + c) * HW_ + pxb);
        float4 f0 = qc[0 * 256 + t];
        float4 f1 = qc[1 * 256 + t];
        float4 f2 = qc[2 * 256 + t];
        d0.x += f0.x * vc; d0.y += f0.y * vc; d0.z += f0.z * vc; d0.w += f0.w * vc;
        s0.x += f0.x * f0.x; s0.y += f0.y * f0.y; s0.z += f0.z * f0.z; s0.w += f0.w * f0.w;
        d1.x += f1.x * vc; d1.y += f1.y * vc; d1.z += f1.z * vc; d1.w += f1.w * vc;
        s1.x += f1.x * f1.x; s1.y += f1.y * f1.y; s1.z += f1.z * f1.z; s1.w += f1.w * f1.w;
        d2.x += f2.x * vc; d2.y += f2.y * vc; d2.z += f2.z * vc; d2.w += f2.w * vc;
        s2.x += f2.x * f2.x; s2.y += f2.y * f2.y; s2.z += f2.z * f2.z; s2.w += f2.w * f2.w;
    }

    size_t base = ((size_t)(b * NCH + ch) * HW_ + pxb) / 4;
    float4* od = (float4*)wsd;
    float4* os = (float4*)wss;
    od[base + 0 * 256 + t] = d0;
    od[base + 1 * 256 + t] = d1;
    od[base + 2 * 256 + t] = d2;
    os[base + 0 * 256 + t] = s0;
    os[base + 1 * 256 + t] = s1;
    os[base + 2 * 256 + t] = s2;
}

// Score pass 2: reduce NCH chunk-partials per pixel, write both logit planes.
__global__ __launch_bounds__(256) void k_score2(const float* __restrict__ wsd,
                                                const float* __restrict__ wss,
                                                float* __restrict__ out) {
    int px = blockIdx.x * 256 + threadIdx.x;  // < B_*HW_
    int b = px / HW_;
    int p = px - b * HW_;

    float d = 0.0f, s2 = 0.0f;
#pragma unroll
    for (int ch = 0; ch < NCH; ++ch) {
        size_t idx = (size_t)(b * NCH + ch) * HW_ + p;
        d += wsd[idx];
        s2 += wss[idx];
    }
    float sv = d / fmaxf(sqrtf(s2), 1e-12f);
    float o = sv / TEMP_V;
    float* ob = out + (size_t)b * 2 * HW_;
    ob[p] = -o;
    ob[HW_ + p] = o;
}

extern "C" void kernel_launch(void* const* d_in, const int* in_sizes, int n_in,
                              void* d_out, int out_size, void* d_ws, size_t ws_size,
                              hipStream_t stream) {
    const float* support_feats = (const float*)d_in[0];
    const int* support_masks = (const int*)d_in[1];
    const float* query_feats = (const float*)d_in[2];
    const int* anchor_pos = (const int*)d_in[3];
    const int* anchor_sample = (const int*)d_in[4];
    const int* anchor_radius = (const int*)d_in[5];
    float* out = (float*)d_out;

    float* ws = (float*)d_ws;
    float* ws_partial = ws;                 // S*C = 1536
    float* ws_msum = ws_partial + S_ * C_;  // 64
    float* ws_proto = ws_msum + M_;         // M*C = 24576
    float* ws_v = ws_proto + M_ * C_;       // 384
    float* ws_fg = ws_v + C_;               // 1
    float* ws_dot = ws_fg + 1;              // B*NCH*HW = 2359296
    float* ws_sq = ws_dot + (size_t)B_ * NCH * HW_;

    k_prep<<<NB_PREP, 256, 0, stream>>>(support_feats, support_masks, anchor_pos,
                                        anchor_sample, anchor_radius,
                                        ws_partial, ws_proto, ws_msum, ws_fg);
    k_finalize<<<1, 256, 0, stream>>>(ws_partial, ws_msum, ws_proto, ws_fg, ws_v);
    k_score1<<<NB_S1, 256, 0, stream>>>(query_feats, ws_v, ws_dot, ws_sq);
    k_score2<<<NB_S2, 256, 0, stream>>>(ws_dot, ws_sq, out);
}